// Round 1
// 401.745 us; speedup vs baseline: 1.1815x; 1.1815x over previous
//
#include <hip/hip_runtime.h>
#include <stdint.h>

// ContextPeftAdaptorLora on MI355X.
// Strategy: fold the 4 rank-16 LoRA adaptors into the K dimension of the base
// GEMM:  out = [x | mask*H] @ [W | 2*Bw]^T + b   with K' = 2048 + 64 = 2112.
// Pass1a: convert x->bf16 into Xaug AND compute PARTIAL H = x @ A^T (MFMA),
//         split 4-ways over K so the grid is 1024 blocks (4/CU) instead of
//         256 (1/CU). Previous fused pass1 was latency-bound at 11.5%
//         occupancy / 865 GB/s.
// Pass1b: reduce the 4 partials, apply per-adaptor mask, write Xaug H cols.
// Pass2:  convert W->bf16 and scaled Bw into Waug.
// Pass3:  m97-style 128x128 bf16 MFMA GEMM with global_load_lds(16B) staging
//         and XOR-swizzled LDS chunk layout (swizzle on global source side).

typedef __attribute__((ext_vector_type(8))) short bf16x8;   // 8 bf16 = 4 VGPR
typedef __attribute__((ext_vector_type(4))) float f32x4;    // MFMA C/D
typedef __attribute__((ext_vector_type(4))) unsigned short u16x4;
typedef __attribute__((ext_vector_type(8))) unsigned short u16x8;

#define GAS __attribute__((address_space(1)))
#define LAS __attribute__((address_space(3)))

static constexpr int BB   = 4;
static constexpr int SS   = 4096;
static constexpr int DIN  = 2048;
static constexpr int DOUT = 2048;
static constexpr int NADP = 4;
static constexpr int RR   = 16;
static constexpr int M    = BB * SS;          // 16384 rows
static constexpr int KA   = DIN + NADP * RR;  // 2112 augmented K
static constexpr float SCALE = 2.0f;          // lora_alpha / r

static constexpr int KSPLIT = 4;              // H K-reduction split factor
static constexpr int KCH    = DIN / KSPLIT;   // 512 K per block

static_assert(KA % 64 == 0, "K-loop needs BK=64 divisibility");

__device__ __forceinline__ unsigned short f2bf(float f) {
  union { float f; uint32_t u; } v; v.f = f;
  uint32_t u = v.u;
  // round-to-nearest-even
  return (unsigned short)((u + 0x7FFFu + ((u >> 16) & 1u)) >> 16);
}

// ---------------------------------------------------------------------------
// Pass 1a: rows in blocks of 64, K in blocks of 512 (KSPLIT=4). Streams its
// x panel once: converts to bf16 (written to Xaug cols [kBase,kBase+512)) and
// accumulates partial H = x @ A_flat^T over its K slice via 16x16x32 bf16
// MFMA on staged LDS chunks. Epilogue writes f32 partials to Hpart[ks][M][64].
// Grid = 1024 blocks -> 4 blocks/CU (vs 1 before): barriers/latency overlap.
// ---------------------------------------------------------------------------
__global__ __launch_bounds__(256) void pass1a_conv_hpart(
    const float* __restrict__ x, const float* __restrict__ A,
    unsigned short* __restrict__ Xaug, float* __restrict__ Hpart)
{
  __shared__ unsigned short xb[64 * 64];  // [row][k] bf16, 8 KB
  __shared__ unsigned short ab[64 * 64];  // [j][k]   bf16, 8 KB

  const int tid = threadIdx.x;
  const int rb = blockIdx.x >> 2;         // 0..255 row-block
  const int ks = blockIdx.x & 3;          // 0..3   K-slice
  const int rowBase = rb * 64;
  const int kBase = ks * KCH;
  const int w = tid >> 6, lane = tid & 63;
  const int quad = lane >> 4, m16 = lane & 15;

  f32x4 acc[4];
  #pragma unroll
  for (int j = 0; j < 4; ++j) acc[j] = f32x4{0.f, 0.f, 0.f, 0.f};

  for (int kc = kBase; kc < kBase + KCH; kc += 64) {
    __syncthreads();  // protect LDS against overwrite while prior MFMA reads run
    #pragma unroll
    for (int l = 0; l < 4; ++l) {
      int v = l * 256 + tid;        // float4-chunk id, 0..1023
      int r = v >> 4;               // row (0..63)
      int k = (v & 15) * 4;         // k offset (0..60)
      float4 xv = *(const float4*)(x + (size_t)(rowBase + r) * DIN + kc + k);
      u16x4 xq = { f2bf(xv.x), f2bf(xv.y), f2bf(xv.z), f2bf(xv.w) };
      *(u16x4*)(xb + r * 64 + k) = xq;
      *(u16x4*)(Xaug + (size_t)(rowBase + r) * KA + kc + k) = xq;
      float4 av = *(const float4*)(A + (size_t)r * DIN + kc + k);  // j = r
      u16x4 aq = { f2bf(av.x), f2bf(av.y), f2bf(av.z), f2bf(av.w) };
      *(u16x4*)(ab + r * 64 + k) = aq;
    }
    __syncthreads();
    // wave w computes H rows [w*16, w*16+16) x all 64 j
    #pragma unroll
    for (int s = 0; s < 2; ++s) {
      bf16x8 af = *(const bf16x8*)(xb + (w * 16 + m16) * 64 + s * 32 + quad * 8);
      #pragma unroll
      for (int jt = 0; jt < 4; ++jt) {
        bf16x8 bfg = *(const bf16x8*)(ab + (jt * 16 + m16) * 64 + s * 32 + quad * 8);
        acc[jt] = __builtin_amdgcn_mfma_f32_16x16x32_bf16(af, bfg, acc[jt], 0, 0, 0);
      }
    }
  }

  // Epilogue: Hpart[ks][row][j] = partial H over this K slice.
  // C/D layout: col = lane&15, row = quad*4 + reg  [m89/m91 verified]
  const int grow0 = rowBase + w * 16 + quad * 4;
  #pragma unroll
  for (int jt = 0; jt < 4; ++jt) {
    #pragma unroll
    for (int r = 0; r < 4; ++r) {
      int grow = grow0 + r;
      Hpart[(((size_t)ks * M + grow) << 6) + jt * 16 + m16] = acc[jt][r];
    }
  }
}

// ---------------------------------------------------------------------------
// Pass 1b: H[row,j] = sum_ks Hpart[ks][row][j]; apply mask[n=j/16, row];
// write bf16 into Xaug cols [2048, 2112). ~17 MB read, 2 MB write.
// ---------------------------------------------------------------------------
__global__ __launch_bounds__(256) void pass1b_reduce_mask(
    const float* __restrict__ Hpart, const float* __restrict__ mask,
    unsigned short* __restrict__ Xaug)
{
  const int idx = blockIdx.x * 256 + threadIdx.x;  // 0 .. M*64-1
  const int row = idx >> 6;
  const int j   = idx & 63;
  float s = 0.f;
  #pragma unroll
  for (int ks = 0; ks < KSPLIT; ++ks)
    s += Hpart[(((size_t)ks * M) << 6) + idx];
  s *= mask[(size_t)(j >> 4) * M + row];
  Xaug[(size_t)row * KA + DIN + j] = f2bf(s);
}

// ---------------------------------------------------------------------------
// Pass 2: Waug[col, 0:2048) = bf16(W[col,:]);  Waug[col, 2048+n*16+r] =
// bf16(SCALE * Bw[n, col, r]).
// ---------------------------------------------------------------------------
__global__ __launch_bounds__(256) void pass2_wcvt(
    const float* __restrict__ W, const float* __restrict__ Bw,
    unsigned short* __restrict__ Waug)
{
  const int idx = blockIdx.x * 256 + threadIdx.x;  // 0..524287
  const int row = idx >> 8;          // 2048 rows, 256 8-elem chunks each
  const int k   = (idx & 255) * 8;
  float4 a = *(const float4*)(W + (size_t)row * DIN + k);
  float4 b = *(const float4*)(W + (size_t)row * DIN + k + 4);
  u16x8 q = { f2bf(a.x), f2bf(a.y), f2bf(a.z), f2bf(a.w),
              f2bf(b.x), f2bf(b.y), f2bf(b.z), f2bf(b.w) };
  *(u16x8*)(Waug + (size_t)row * KA + k) = q;

  if (idx < DOUT * NADP) {           // 8192 threads build the Bwcat columns
    const int col = idx >> 2, n = idx & 3;
    const float* src = Bw + (size_t)n * DOUT * RR + (size_t)col * RR;
    #pragma unroll
    for (int t = 0; t < 4; ++t) {
      float4 bv = *(const float4*)(src + 4 * t);
      u16x4 qq = { f2bf(SCALE * bv.x), f2bf(SCALE * bv.y),
                   f2bf(SCALE * bv.z), f2bf(SCALE * bv.w) };
      *(u16x4*)(Waug + (size_t)col * KA + DIN + n * 16 + 4 * t) = qq;
    }
  }
}

// ---------------------------------------------------------------------------
// Pass 3: bf16 GEMM, out[M, DOUT] = Xaug @ Waug^T + b.
// 128x128 tile, BK=64, 4 waves (2x2), each wave 4x4 tiles of 16x16x32 MFMA.
// Staging via global_load_lds width=16; LDS chunk layout XOR-swizzled:
// LDS[r][c'] holds global chunk (r, c' ^ (r&7)) so fragment b128 reads are
// conflict-free (2-way only). Swizzle is applied on the global address side
// because global_load_lds destination is forced to base + lane*16.
// ---------------------------------------------------------------------------
__global__ __launch_bounds__(256, 3) void gemm_aug(
    const unsigned short* __restrict__ Xa, const unsigned short* __restrict__ Wa,
    const float* __restrict__ bias, float* __restrict__ out)
{
  __shared__ unsigned short lds_a[128 * 64];  // 16 KB
  __shared__ unsigned short lds_b[128 * 64];  // 16 KB

  const int tid = threadIdx.x;
  const int bn = blockIdx.x, bm = blockIdx.y;
  const int w = tid >> 6, lane = tid & 63;
  const int wm = w >> 1, wn = w & 1;          // 2x2 wave grid, 64x64 each
  const int quad = lane >> 4, m16 = lane & 15;

  f32x4 acc[4][4];
  #pragma unroll
  for (int i = 0; i < 4; ++i)
    #pragma unroll
    for (int j = 0; j < 4; ++j) acc[i][j] = f32x4{0.f, 0.f, 0.f, 0.f};

  const unsigned short* ga = Xa + (size_t)bm * 128 * KA;
  const unsigned short* gb = Wa + (size_t)bn * 128 * KA;

  // staging descriptors: thread covers LDS 16B-chunk p = l*256 + tid
  size_t goff[4];
  int ldso[4];
  #pragma unroll
  for (int l = 0; l < 4; ++l) {
    int p = l * 256 + tid;
    int r = p >> 3;                 // tile row 0..127
    int c = (p & 7) ^ (r & 7);      // swizzled global chunk
    goff[l] = (size_t)r * KA + c * 8;          // ushort offset (+k0 later)
    ldso[l] = (l * 256 + (tid & ~63)) * 8;     // wave-uniform LDS base (ushorts)
  }

  for (int k0 = 0; k0 < KA; k0 += 64) {
    __syncthreads();  // all waves done reading previous tile
    #pragma unroll
    for (int l = 0; l < 4; ++l) {
      __builtin_amdgcn_global_load_lds((const GAS void*)(ga + goff[l] + k0),
                                       (LAS void*)(lds_a + ldso[l]), 16, 0, 0);
      __builtin_amdgcn_global_load_lds((const GAS void*)(gb + goff[l] + k0),
                                       (LAS void*)(lds_b + ldso[l]), 16, 0, 0);
    }
    __syncthreads();  // compiler drains vmcnt(0) before s_barrier -> LDS valid

    #pragma unroll
    for (int s = 0; s < 2; ++s) {
      const int cc = ((s * 4 + quad) ^ (m16 & 7)) * 8;  // swizzled k-chunk
      bf16x8 af[4], bfg[4];
      #pragma unroll
      for (int i = 0; i < 4; ++i)
        af[i] = *(const bf16x8*)(lds_a + (wm * 64 + i * 16 + m16) * 64 + cc);
      #pragma unroll
      for (int j = 0; j < 4; ++j)
        bfg[j] = *(const bf16x8*)(lds_b + (wn * 64 + j * 16 + m16) * 64 + cc);
      #pragma unroll
      for (int i = 0; i < 4; ++i)
        #pragma unroll
        for (int j = 0; j < 4; ++j)
          acc[i][j] = __builtin_amdgcn_mfma_f32_16x16x32_bf16(af[i], bfg[j],
                                                              acc[i][j], 0, 0, 0);
    }
  }

  // Epilogue: C/D layout col = lane&15, row = quad*4 + reg
  float bv[4];
  #pragma unroll
  for (int j = 0; j < 4; ++j) bv[j] = bias[bn * 128 + wn * 64 + j * 16 + m16];
  #pragma unroll
  for (int i = 0; i < 4; ++i) {
    const int row0 = bm * 128 + wm * 64 + i * 16 + quad * 4;
    #pragma unroll
    for (int j = 0; j < 4; ++j) {
      const int col = bn * 128 + wn * 64 + j * 16 + m16;
      #pragma unroll
      for (int r = 0; r < 4; ++r)
        out[(size_t)(row0 + r) * DOUT + col] = acc[i][j][r] + bv[j];
    }
  }
}

// ---------------------------------------------------------------------------
extern "C" void kernel_launch(void* const* d_in, const int* in_sizes, int n_in,
                              void* d_out, int out_size, void* d_ws, size_t ws_size,
                              hipStream_t stream) {
  const float* x    = (const float*)d_in[0];  // [4,4096,2048]
  const float* mask = (const float*)d_in[1];  // [4,4,4096,1]
  const float* W    = (const float*)d_in[2];  // [2048,2048]
  const float* bias = (const float*)d_in[3];  // [2048]
  const float* A    = (const float*)d_in[4];  // [4,16,2048] -> flat [64,2048]
  const float* Bw   = (const float*)d_in[5];  // [4,2048,16]
  float* out = (float*)d_out;

  // workspace layout:
  //   Xaug  [16384,2112] bf16 = 69,206,016 B
  //   Waug  [ 2048,2112] bf16 =  8,650,752 B
  //   Hpart [4,16384,64] f32  = 16,777,216 B
  // total = 94,633,984 bytes of d_ws
  unsigned short* Xaug = (unsigned short*)d_ws;
  unsigned short* Waug = Xaug + (size_t)M * KA;
  float* Hpart = (float*)(Waug + (size_t)DOUT * KA);

  pass1a_conv_hpart<<<dim3(M / 64 * KSPLIT), dim3(256), 0, stream>>>(x, A, Xaug, Hpart);
  pass1b_reduce_mask<<<dim3(M * 64 / 256), dim3(256), 0, stream>>>(Hpart, mask, Xaug);
  pass2_wcvt<<<dim3((DOUT * (DIN / 8)) / 256), dim3(256), 0, stream>>>(W, Bw, Waug);
  gemm_aug<<<dim3(DOUT / 128, M / 128), dim3(256), 0, stream>>>(Xaug, Waug, bias, out);
}